// Round 25
// baseline (113.871 us; speedup 1.0000x reference)
//
#include <hip/hip_runtime.h>
#include <hip/hip_bf16.h>

typedef _Float16 f16x8 __attribute__((ext_vector_type(8)));
typedef _Float16 h2    __attribute__((ext_vector_type(2)));
typedef float    f32x4v __attribute__((ext_vector_type(4)));
typedef float    f32x2 __attribute__((ext_vector_type(2)));

#define NEG_SLOPE 0.2f
#define NSHARD 8
#define SHARD_CAP 1024    // staging slots per (bucket, shard)
#define BKT_CAP (NSHARD*SHARD_CAP)   // fixed csr region per bucket
#define CE 1024           // edges per prepfill block (4/thread, register-held)
#define LOG2E 1.44269504088896f

__device__ __forceinline__ ushort f2h_bits(float f){ _Float16 h=(_Float16)f; return __builtin_bit_cast(ushort, h); }
__device__ __forceinline__ h2 uash2(unsigned u){ return __builtin_bit_cast(h2, u); }
__device__ __forceinline__ h2 habs(h2 v){ return __builtin_bit_cast(h2, __builtin_bit_cast(unsigned, v) & 0x7fff7fffu); }
// acc += (f16 half of xs) * ex, exact (f16 widened to f32 inside the FMA)
__device__ __forceinline__ void fmamix_lo(float& acc, h2 xs, float ex){
    asm("v_fma_mix_f32 %0, %1, %2, %0 op_sel:[0,0,0] op_sel_hi:[1,0,0]" : "+v"(acc) : "v"(xs), "v"(ex));
}
__device__ __forceinline__ void fmamix_hi(float& acc, h2 xs, float ex){
    asm("v_fma_mix_f32 %0, %1, %2, %0 op_sel:[1,0,0] op_sel_hi:[1,0,0]" : "+v"(acc) : "v"(xs), "v"(ex));
}

// ---------------- K0: prepfill — weights->f16 + bucket staging; NO global atomics on cnt64 ----------------
// staged entry: src(16b) | etype<<16 (3b) | dstloc<<19 (8b)
__global__ __launch_bounds__(256) void k_prepfill(const float* __restrict__ Wl, const float* __restrict__ Wr,
    const float* __restrict__ We, const float* __restrict__ att,
    ushort* __restrict__ Wt, ushort* __restrict__ Web, ushort* __restrict__ att_h,
    ushort* __restrict__ att6, ushort* __restrict__ att4,
    const int* __restrict__ src, const int* __restrict__ dst, const float* __restrict__ ea,
    int* __restrict__ bkt_cnt, unsigned* __restrict__ sta, int E)
{
    __shared__ int hist[256], gbase[256], wcur[256];
    int tid = threadIdx.x;
    int idx = blockIdx.x*256 + tid;
    if (idx < 256*128) {
        int c = idx >> 7, k = idx & 127;
        float v = (c < 128) ? Wl[k*128 + c] : Wr[k*128 + (c-128)];
        Wt[idx] = f2h_bits(v);
    }
    if (idx < 8*128) Web[idx] = f2h_bits(We[idx]);
    if (idx < 128) {
        float a = att[idx];
        att_h[idx] = f2h_bits(a);
        att6[idx]  = f2h_bits(0.6f*LOG2E*a);      // lrelu-decomposed, log2e folded (k_node uses exp2)
        att4[idx]  = f2h_bits(0.4f*LOG2E*a);
    }

    hist[tid] = 0; wcur[tid] = 0;
    __syncthreads();
    int shard = blockIdx.x & (NSHARD-1);
    int e0 = blockIdx.x*CE;
    int ne = min(CE, E - e0);
    unsigned ent[4];
    int ebkt[4];
    #pragma unroll
    for (int j=0;j<4;++j){
        int i = tid + j*256;
        ebkt[j] = -1;
        if (i < ne){
            int e = e0 + i;
            int d = dst[e];
            const float* a = ea + (size_t)e*8;
            float4 u0 = *(const float4*)a;
            float4 u1 = *(const float4*)(a + 4);
            float v[8] = {u0.x,u0.y,u0.z,u0.w,u1.x,u1.y,u1.z,u1.w};
            int bt = 0;                            // one-hot: nonzero component (value==1.0)
            #pragma unroll
            for (int q=0;q<8;++q) if (v[q] != 0.f) bt = q;
            int b = d >> 8;
            ent[j] = (unsigned)(src[e] & 0xFFFF) | ((unsigned)bt << 16) | ((unsigned)(d & 255) << 19);
            ebkt[j] = b;
            atomicAdd(&hist[b], 1);
        }
    }
    __syncthreads();
    int v = hist[tid];
    if (v > 0) gbase[tid] = atomicAdd(&bkt_cnt[shard*256 + tid], v);
    __syncthreads();
    #pragma unroll
    for (int j=0;j<4;++j){
        if (ebkt[j] >= 0){
            int b = ebkt[j];
            int r = atomicAdd(&wcur[b], 1);
            sta[((size_t)b*NSHARD + shard)*SHARD_CAP + gbase[b] + r] = ent[j];  // L2-merged run
        }
    }
}

// ---------------- K1: fill2 — 2 blocks/bucket; LDS type-count -> cnt64/deg/csr_off (4-aligned), scatter ----------------
__global__ __launch_bounds__(256) void k_fill2(const unsigned* __restrict__ sta,
    const int* __restrict__ bkt_cnt, unsigned long long* __restrict__ cnt64,
    int* __restrict__ deg_i, int* __restrict__ csr_off, int* __restrict__ csr_pack)
{
    __shared__ unsigned long long c64[256];
    __shared__ int s[256];
    __shared__ int sexc[256];
    __shared__ int lcur[256];
    int b = blockIdx.x >> 1, half = blockIdx.x & 1;
    int tid = threadIdx.x;
    c64[tid] = 0; lcur[tid] = 0;
    __syncthreads();
    // count pass: all shards, all entries (both halves -> full 256-node degrees for the scan)
    for (int k = 0; k < NSHARD; ++k){
        int cnt = bkt_cnt[k*256 + b];
        const unsigned* sb = sta + ((size_t)b*NSHARD + k)*SHARD_CAP;
        for (int i = tid; i < cnt; i += 256){
            unsigned u = sb[i];
            int dl = (u >> 19) & 255;
            int bt = (u >> 16) & 7;
            atomicAdd(&c64[dl], 1ull << (8*bt));
        }
    }
    __syncthreads();
    unsigned long long cv = c64[tid];
    int v = (int)((cv * 0x0101010101010101ull) >> 56);   // degree
    int vp = (v + 3) & ~3;                         // pad region to mult-of-4 (16B-aligned quad loads)
    s[tid] = vp;
    __syncthreads();
    #pragma unroll
    for (int off=1; off<256; off<<=1){
        int t = (tid >= off) ? s[tid-off] : 0;
        __syncthreads();
        s[tid] += t;
        __syncthreads();
    }
    int loc = s[tid] - vp;                         // bucket-local exclusive offset (mult of 4)
    sexc[tid] = loc;
    int node = b*256 + tid;
    if ((tid >> 7) == half){
        cnt64[node] = cv;
        deg_i[node] = v;
        csr_off[node] = b*BKT_CAP + loc;           // bucket-strided csr region, 16B-aligned
    }
    __syncthreads();
    int base = b*BKT_CAP;
    for (int k = 0; k < NSHARD; ++k){
        int cnt = bkt_cnt[k*256 + b];
        const unsigned* sb = sta + ((size_t)b*NSHARD + k)*SHARD_CAP;
        for (int i = tid; i < cnt; i += 256){
            unsigned u = sb[i];
            int dl = (u >> 19) & 255;
            if ((dl >> 7) != half) continue;
            int slot = base + sexc[dl] + atomicAdd(&lcur[dl], 1);
            csr_pack[slot] = (int)(u & 0xFFFFu) | (int)(((u >> 16) & 7u) << 24);
        }
    }
}

// ---------------- K2: MFMA GEMM — 32 rows/wave (shared B-fragments), wave-local staging ----------------
__global__ __launch_bounds__(256) void k_gemm(const float* __restrict__ x, const ushort* __restrict__ Wt,
    const float* __restrict__ bl, const float* __restrict__ br,
    const ushort* __restrict__ Web, const ushort* __restrict__ att_h,
    const unsigned long long* __restrict__ cnt64,
    ushort* __restrict__ xl, ushort* __restrict__ xr, float* __restrict__ expd_self, int Nn)
{
    __shared__ ushort S[4][32*256];               // 16KB per wave (wave-local; no cross-wave sharing)
    int tid = threadIdx.x;
    int wave = tid >> 6, lane = tid & 63;
    int l15 = lane & 15, l4 = lane >> 4;
    int row0 = blockIdx.x*128 + wave*32;

    f16x8 afragA[4], afragB[4];
    int growA = row0 + l15, growB = row0 + 16 + l15;
    bool rokA = growA < Nn, rokB = growB < Nn;
    const float* xpA = x + (size_t)growA*128 + l4*8;
    const float* xpB = x + (size_t)growB*128 + l4*8;
    #pragma unroll
    for (int ks=0; ks<4; ++ks){
        float4 a = make_float4(0,0,0,0), b = make_float4(0,0,0,0);
        if (rokA) { a = *(const float4*)(xpA + ks*32); b = *(const float4*)(xpA + ks*32 + 4); }
        afragA[ks] = (f16x8){ (_Float16)a.x,(_Float16)a.y,(_Float16)a.z,(_Float16)a.w,
                              (_Float16)b.x,(_Float16)b.y,(_Float16)b.z,(_Float16)b.w };
        float4 c = make_float4(0,0,0,0), d = make_float4(0,0,0,0);
        if (rokB) { c = *(const float4*)(xpB + ks*32); d = *(const float4*)(xpB + ks*32 + 4); }
        afragB[ks] = (f16x8){ (_Float16)c.x,(_Float16)c.y,(_Float16)c.z,(_Float16)c.w,
                              (_Float16)d.x,(_Float16)d.y,(_Float16)d.z,(_Float16)d.w };
    }

    ushort* sw_base = &S[wave][0];
    #pragma unroll
    for (int nf=0; nf<16; ++nf){
        f32x4v accA = (f32x4v){0.f,0.f,0.f,0.f};
        f32x4v accB = (f32x4v){0.f,0.f,0.f,0.f};
        #pragma unroll
        for (int ks=0; ks<4; ++ks){
            const ushort* bp = Wt + (size_t)(nf*16 + l15)*128 + ks*32 + l4*8;
            f16x8 bf = *(const f16x8*)(const void*)bp;
            accA = __builtin_amdgcn_mfma_f32_16x16x32_f16(bf, afragA[ks], accA, 0,0,0);
            accB = __builtin_amdgcn_mfma_f32_16x16x32_f16(bf, afragB[ks], accB, 0,0,0);
        }
        int c0 = nf*16 + l4*4;
        const float* bp2 = (c0 < 128) ? (bl + c0) : (br + (c0-128));
        float4 bv = *(const float4*)bp2;
        int sw = c0 ^ ((l15 & 7) << 2);           // row&7 == (16+row)&7: same swizzle both halves
        h2 pa0 = { (_Float16)(accA[0] + bv.x), (_Float16)(accA[1] + bv.y) };
        h2 pa1 = { (_Float16)(accA[2] + bv.z), (_Float16)(accA[3] + bv.w) };
        *(uint2*)(&sw_base[l15*256 + sw]) = make_uint2(__builtin_bit_cast(unsigned, pa0),
                                                       __builtin_bit_cast(unsigned, pa1));
        h2 pb0 = { (_Float16)(accB[0] + bv.x), (_Float16)(accB[1] + bv.y) };
        h2 pb1 = { (_Float16)(accB[2] + bv.z), (_Float16)(accB[3] + bv.w) };
        *(uint2*)(&sw_base[(16 + l15)*256 + sw]) = make_uint2(__builtin_bit_cast(unsigned, pb0),
                                                              __builtin_bit_cast(unsigned, pb1));
    }
    asm volatile("s_waitcnt lgkmcnt(0)");         // wave-local LDS produce->consume

    #pragma unroll
    for (int pass=0; pass<8; ++pass){
        int row = pass*4 + l4;
        int gr = row0 + row;
        if (gr < Nn){
            int cu = l15*8;
            int m = (row & 7) << 2;
            uint2 a0 = *(const uint2*)(&sw_base[row*256 + (cu ^ m)]);
            uint2 a1 = *(const uint2*)(&sw_base[row*256 + ((cu+4) ^ m)]);
            *(uint4*)(xl + (size_t)gr*128 + cu) = make_uint4(a0.x, a0.y, a1.x, a1.y);
            uint2 b0 = *(const uint2*)(&sw_base[row*256 + ((128+cu) ^ m)]);
            uint2 b1 = *(const uint2*)(&sw_base[row*256 + ((128+cu+4) ^ m)]);
            *(uint4*)(xr + (size_t)gr*128 + cu) = make_uint4(b0.x, b0.y, b1.x, b1.y);
        }
    }

    // Fused self-loop score, 2 passes over the 32 staged rows; tables computed once.
    h2 at2v[16];
    {
        const ushort* ap = att_h + l4*32;
        uint4 a0 = *(const uint4*)ap;
        uint4 a1 = *(const uint4*)(ap + 8);
        uint4 a2 = *(const uint4*)(ap + 16);
        uint4 a3 = *(const uint4*)(ap + 24);
        at2v[0]=uash2(a0.x); at2v[1]=uash2(a0.y); at2v[2]=uash2(a0.z); at2v[3]=uash2(a0.w);
        at2v[4]=uash2(a1.x); at2v[5]=uash2(a1.y); at2v[6]=uash2(a1.z); at2v[7]=uash2(a1.w);
        at2v[8]=uash2(a2.x); at2v[9]=uash2(a2.y); at2v[10]=uash2(a2.z); at2v[11]=uash2(a2.w);
        at2v[12]=uash2(a3.x); at2v[13]=uash2(a3.y); at2v[14]=uash2(a3.z); at2v[15]=uash2(a3.w);
    }
    const h2 z2  = {(_Float16)0.f, (_Float16)0.f};
    const h2 c02 = {(_Float16)NEG_SLOPE, (_Float16)NEG_SLOPE};
    #pragma unroll
    for (int pp=0; pp<2; ++pp){
        int row = pp*16 + l15;
        int grow = row0 + row;
        if (grow >= Nn) continue;
        unsigned long long cv = cnt64[grow];
        int deg = (int)((cv * 0x0101010101010101ull) >> 56);
        float inv = 1.f / fmaxf((float)deg, 1.f);
        h2 wt[8];
        #pragma unroll
        for (int t=0;t<8;++t){
            float w = (float)((cv >> (8*t)) & 0xff) * inv;
            wt[t] = (h2){ (_Float16)w, (_Float16)w };
        }
        h2 emb[16];
        #pragma unroll
        for (int j=0;j<16;++j) emb[j] = (h2){(_Float16)0.f,(_Float16)0.f};
        #pragma unroll
        for (int t=0;t<8;++t){
            const ushort* wp = Web + t*128 + l4*32;
            uint4 u0 = *(const uint4*)wp;
            uint4 u1 = *(const uint4*)(wp + 8);
            uint4 u2 = *(const uint4*)(wp + 16);
            uint4 u3 = *(const uint4*)(wp + 24);
            emb[0]+=wt[t]*uash2(u0.x); emb[1]+=wt[t]*uash2(u0.y); emb[2]+=wt[t]*uash2(u0.z); emb[3]+=wt[t]*uash2(u0.w);
            emb[4]+=wt[t]*uash2(u1.x); emb[5]+=wt[t]*uash2(u1.y); emb[6]+=wt[t]*uash2(u1.z); emb[7]+=wt[t]*uash2(u1.w);
            emb[8]+=wt[t]*uash2(u2.x); emb[9]+=wt[t]*uash2(u2.y); emb[10]+=wt[t]*uash2(u2.z); emb[11]+=wt[t]*uash2(u2.w);
            emb[12]+=wt[t]*uash2(u3.x); emb[13]+=wt[t]*uash2(u3.y); emb[14]+=wt[t]*uash2(u3.z); emb[15]+=wt[t]*uash2(u3.w);
        }
        float p0 = 0.f, p1 = 0.f;
        int m = (row & 7) << 2;
        #pragma unroll
        for (int j=0;j<8;++j){
            int c0 = l4*32 + j*4;
            uint2 xlu = *(const uint2*)(&sw_base[row*256 + (c0 ^ m)]);
            uint2 xru = *(const uint2*)(&sw_base[row*256 + ((128+c0) ^ m)]);
            #pragma unroll
            for (int s2=0;s2<2;++s2){
                h2 v = (uash2(s2 ? xlu.y : xlu.x) + uash2(s2 ? xru.y : xru.x)) + emb[j*2+s2];
                h2 r = __builtin_elementwise_max(v, z2);
                h2 mm = __builtin_elementwise_min(v, z2);
                r = r + c02*mm;
                if (j < 4) p0 = __builtin_amdgcn_fdot2(at2v[j*2+s2], r, p0, false);
                else       p1 = __builtin_amdgcn_fdot2(at2v[j*2+s2], r, p1, false);
            }
        }
        *(float2*)(expd_self + (size_t)grow*8 + l4*2) = make_float2(__expf(p0), __expf(p1));
    }
}

// ---------------- K3: fused per-node pass — 16 edges/round (4 per group), sanitized indices ----------------
__global__ __launch_bounds__(128) void k_node(const int* __restrict__ deg_i, const int* __restrict__ csr_off,
    const int* __restrict__ csr_pack,
    const ushort* __restrict__ xl, const ushort* __restrict__ xr, const ushort* __restrict__ Web,
    const ushort* __restrict__ att6, const ushort* __restrict__ att4, const float* __restrict__ expd_self,
    const float* __restrict__ bias, const float* __restrict__ lnw, const float* __restrict__ lnb,
    float* __restrict__ out, int Nn)
{
    __shared__ ushort xrw[2][8][16][8];           // [wave][etype][lane-l][8 f16] = 4KB
    int wv = threadIdx.x >> 6, lane = threadIdx.x & 63;
    int n = blockIdx.x*2 + wv;
    if (n >= Nn) return;
    int g = lane >> 4, l = lane & 15;

    h2 a6[4], a4[4];
    {
        uint4 u6 = *(const uint4*)(att6 + l*8);
        uint4 u4 = *(const uint4*)(att4 + l*8);
        a6[0]=uash2(u6.x); a6[1]=uash2(u6.y); a6[2]=uash2(u6.z); a6[3]=uash2(u6.w);
        a4[0]=uash2(u4.x); a4[1]=uash2(u4.y); a4[2]=uash2(u4.z); a4[3]=uash2(u4.w);
    }
    // build xrw[wv][t][l] = xr[n][l*8..] + Web[t][l*8..]; lane (g,l) does types g and g+4
    {
        uint4 ru = *(const uint4*)(xr + (size_t)n*128 + l*8);
        h2 xr2[4] = {uash2(ru.x), uash2(ru.y), uash2(ru.z), uash2(ru.w)};
        #pragma unroll
        for (int tt=0; tt<2; ++tt){
            int t = g + tt*4;
            uint4 wu = *(const uint4*)(Web + t*128 + l*8);
            h2 w0 = uash2(wu.x)+xr2[0], w1 = uash2(wu.y)+xr2[1];
            h2 w2 = uash2(wu.z)+xr2[2], w3 = uash2(wu.w)+xr2[3];
            *(uint4*)(&xrw[wv][t][l][0]) = make_uint4(__builtin_bit_cast(unsigned,w0), __builtin_bit_cast(unsigned,w1),
                                                      __builtin_bit_cast(unsigned,w2), __builtin_bit_cast(unsigned,w3));
        }
        asm volatile("s_waitcnt lgkmcnt(0)");     // intra-wave LDS produce->consume (no barrier needed)
    }

    int beg = csr_off[n];
    int cnt = deg_i[n];
    float accx[4], accy[4];
    #pragma unroll
    for (int k=0;k<4;++k){ accx[k]=0.f; accy[k]=0.f; }
    float den = 0.f;

    for (int i = 0; i < cnt; i += 16) {
        int e0i = i + 4*g;
        bool v0 = e0i < cnt;
        bool v1 = (e0i + 1) < cnt;
        bool v2 = (e0i + 2) < cnt;
        bool v3 = (e0i + 3) < cnt;
        uint4 pk = *(const uint4*)(csr_pack + beg + (v0 ? e0i : 0));   // 16B aligned (beg mult of 4)
        int s0  = v0 ? (pk.x & 0xFFFFFF) : 0;                          // sanitize: padding holds poison
        int et0 = v0 ? (int)(((unsigned)pk.x) >> 24) : 0;
        int s1  = v1 ? (pk.y & 0xFFFFFF) : 0;
        int et1 = v1 ? (int)(((unsigned)pk.y) >> 24) : 0;
        int s2i = v2 ? (pk.z & 0xFFFFFF) : 0;
        int et2 = v2 ? (int)(((unsigned)pk.z) >> 24) : 0;
        int s3  = v3 ? (pk.w & 0xFFFFFF) : 0;
        int et3 = v3 ? (int)(((unsigned)pk.w) >> 24) : 0;
        uint4 xu0 = *(const uint4*)(xl + (size_t)s0 *128 + l*8);       // 4 independent gathers in flight
        uint4 xu1 = *(const uint4*)(xl + (size_t)s1 *128 + l*8);
        uint4 xu2 = *(const uint4*)(xl + (size_t)s2i*128 + l*8);
        uint4 xu3 = *(const uint4*)(xl + (size_t)s3 *128 + l*8);
        uint4 wu0 = *(const uint4*)(&xrw[wv][et0][l][0]);
        uint4 wu1 = *(const uint4*)(&xrw[wv][et1][l][0]);
        uint4 wu2 = *(const uint4*)(&xrw[wv][et2][l][0]);
        uint4 wu3 = *(const uint4*)(&xrw[wv][et3][l][0]);
        h2 xs0[4] = {uash2(xu0.x), uash2(xu0.y), uash2(xu0.z), uash2(xu0.w)};
        h2 xs1[4] = {uash2(xu1.x), uash2(xu1.y), uash2(xu1.z), uash2(xu1.w)};
        h2 xs2[4] = {uash2(xu2.x), uash2(xu2.y), uash2(xu2.z), uash2(xu2.w)};
        h2 xs3[4] = {uash2(xu3.x), uash2(xu3.y), uash2(xu3.z), uash2(xu3.w)};
        h2 xw0[4] = {uash2(wu0.x), uash2(wu0.y), uash2(wu0.z), uash2(wu0.w)};
        h2 xw1[4] = {uash2(wu1.x), uash2(wu1.y), uash2(wu1.z), uash2(wu1.w)};
        h2 xw2[4] = {uash2(wu2.x), uash2(wu2.y), uash2(wu2.z), uash2(wu2.w)};
        h2 xw3[4] = {uash2(wu3.x), uash2(wu3.y), uash2(wu3.z), uash2(wu3.w)};
        float pa = 0.f, pb = 0.f, pc = 0.f, pd = 0.f;
        #pragma unroll
        for (int k=0;k<4;++k){
            h2 va = xs0[k] + xw0[k];
            pa = __builtin_amdgcn_fdot2(a6[k], va, pa, false);
            pa = __builtin_amdgcn_fdot2(a4[k], habs(va), pa, false);
            h2 vb = xs1[k] + xw1[k];
            pb = __builtin_amdgcn_fdot2(a6[k], vb, pb, false);
            pb = __builtin_amdgcn_fdot2(a4[k], habs(vb), pb, false);
            h2 vc = xs2[k] + xw2[k];
            pc = __builtin_amdgcn_fdot2(a6[k], vc, pc, false);
            pc = __builtin_amdgcn_fdot2(a4[k], habs(vc), pc, false);
            h2 vd = xs3[k] + xw3[k];
            pd = __builtin_amdgcn_fdot2(a6[k], vd, pd, false);
            pd = __builtin_amdgcn_fdot2(a4[k], habs(vd), pd, false);
        }
        pa += __shfl_xor(pa, 1);                   // head score*log2e (2 lanes/head)
        pb += __shfl_xor(pb, 1);
        pc += __shfl_xor(pc, 1);
        pd += __shfl_xor(pd, 1);
        float ex0 = v0 ? exp2f(pa) : 0.f;
        float ex1 = v1 ? exp2f(pb) : 0.f;
        float ex2 = v2 ? exp2f(pc) : 0.f;
        float ex3 = v3 ? exp2f(pd) : 0.f;
        den += (ex0 + ex1) + (ex2 + ex3);
        #pragma unroll
        for (int k=0;k<4;++k){
            fmamix_lo(accx[k], xs0[k], ex0);
            fmamix_hi(accy[k], xs0[k], ex0);
            fmamix_lo(accx[k], xs1[k], ex1);
            fmamix_hi(accy[k], xs1[k], ex1);
            fmamix_lo(accx[k], xs2[k], ex2);
            fmamix_hi(accy[k], xs2[k], ex2);
            fmamix_lo(accx[k], xs3[k], ex3);
            fmamix_hi(accy[k], xs3[k], ex3);
        }
    }

    #pragma unroll
    for (int k=0;k<4;++k){
        accx[k] += __shfl_xor(accx[k], 16); accx[k] += __shfl_xor(accx[k], 32);
        accy[k] += __shfl_xor(accy[k], 16); accy[k] += __shfl_xor(accy[k], 32);
    }
    den += __shfl_xor(den, 16);
    den += __shfl_xor(den, 32);

    // self loop: expd_self precomputed in k_gemm
    {
        float ex = expd_self[(size_t)n*8 + (l >> 1)];
        uint4 su = *(const uint4*)(xl + (size_t)n*128 + l*8);
        den += ex;
        h2 ss[4] = {uash2(su.x), uash2(su.y), uash2(su.z), uash2(su.w)};
        #pragma unroll
        for (int k=0;k<4;++k){
            fmamix_lo(accx[k], ss[k], ex);
            fmamix_hi(accy[k], ss[k], ex);
        }
    }

    float dinv = 1.f/den;
    f32x2 a[4];
    {
        float4 b0 = *(const float4*)(bias + l*8);
        float4 b1 = *(const float4*)(bias + l*8 + 4);
        a[0] = (f32x2){accx[0]*dinv + b0.x, accy[0]*dinv + b0.y};
        a[1] = (f32x2){accx[1]*dinv + b0.z, accy[1]*dinv + b0.w};
        a[2] = (f32x2){accx[2]*dinv + b1.x, accy[2]*dinv + b1.y};
        a[3] = (f32x2){accx[3]*dinv + b1.z, accy[3]*dinv + b1.w};
    }
    float sum = 0.f;
    #pragma unroll
    for (int k=0;k<4;++k) sum += a[k].x + a[k].y;
    #pragma unroll
    for (int off=8; off>0; off>>=1) sum += __shfl_xor(sum, off);
    float mu = sum * (1.f/128.f);
    float vs = 0.f;
    #pragma unroll
    for (int k=0;k<4;++k){ a[k] -= mu; vs += a[k].x*a[k].x + a[k].y*a[k].y; }
    #pragma unroll
    for (int off=8; off>0; off>>=1) vs += __shfl_xor(vs, off);
    float rs = rsqrtf(vs*(1.f/128.f) + 1e-5f);
    float y[8];
    {
        float4 w0 = *(const float4*)(lnw + l*8);
        float4 w1 = *(const float4*)(lnw + l*8 + 4);
        float4 c0 = *(const float4*)(lnb + l*8);
        float4 c1 = *(const float4*)(lnb + l*8 + 4);
        y[0]=a[0].x*rs*w0.x+c0.x; y[1]=a[0].y*rs*w0.y+c0.y;
        y[2]=a[1].x*rs*w0.z+c0.z; y[3]=a[1].y*rs*w0.w+c0.w;
        y[4]=a[2].x*rs*w1.x+c1.x; y[5]=a[2].y*rs*w1.y+c1.y;
        y[6]=a[3].x*rs*w1.z+c1.z; y[7]=a[3].y*rs*w1.w+c1.w;
    }
    #pragma unroll
    for (int j=0;j<8;++j) y[j] = (y[j] > 0.f) ? y[j] : (__expf(y[j]) - 1.f);
    if (lane < 16) {
        float* po = out + (size_t)n*128 + l*8;
        *(float4*)po     = make_float4(y[0],y[1],y[2],y[3]);
        *(float4*)(po+4) = make_float4(y[4],y[5],y[6],y[7]);
    }
}

extern "C" void kernel_launch(void* const* d_in, const int* in_sizes, int n_in,
                              void* d_out, int out_size, void* d_ws, size_t ws_size,
                              hipStream_t stream)
{
    const float* x   = (const float*)d_in[0];
    const int*   src = (const int*)  d_in[1];
    const int*   dst = (const int*)  d_in[2];
    const float* ea  = (const float*)d_in[3];
    const float* Wl  = (const float*)d_in[4];
    const float* bl  = (const float*)d_in[5];
    const float* Wr  = (const float*)d_in[6];
    const float* br  = (const float*)d_in[7];
    const float* We  = (const float*)d_in[8];
    const float* att = (const float*)d_in[9];
    const float* bias= (const float*)d_in[10];
    const float* lnw = (const float*)d_in[11];
    const float* lnb = (const float*)d_in[12];
    float* out = (float*)d_out;

    const int N  = in_sizes[0] / 128;
    const int E  = in_sizes[1];
    const int NP = ((N + 255)/256)*256;
    const int MB = (N + 127)/128;     // 128 rows per gemm block
    const int SB = NP/256;            // buckets (256 nodes each)
    const int PB = (E + CE - 1)/CE;   // prepfill blocks

    char* base = (char*)d_ws;
    size_t o = 0;
    auto alloc = [&](size_t b){ size_t r = o; o += (b + 255) & ~(size_t)255; return r; };
    ushort* Wt       = (ushort*)(base + alloc(256*128*2));
    ushort* Web      = (ushort*)(base + alloc(8*128*2));
    ushort* att_h    = (ushort*)(base + alloc(128*2));
    ushort* att6     = (ushort*)(base + alloc(128*2));
    ushort* att4     = (ushort*)(base + alloc(128*2));
    ushort* xl       = (ushort*)(base + alloc((size_t)MB*128*128*2));
    ushort* xr       = (ushort*)(base + alloc((size_t)MB*128*128*2));
    float*  expd_self= (float*) (base + alloc((size_t)NP*8*4));
    size_t zoff = o;
    int*    bkt_cnt  = (int*)   (base + alloc((size_t)NSHARD*256*4));
    size_t zbytes = o - zoff;
    unsigned long long* cnt64 = (unsigned long long*)(base + alloc((size_t)NP*8));
    int*    deg_i    = (int*)   (base + alloc((size_t)NP*4));
    int*    csr_off  = (int*)   (base + alloc((size_t)NP*4));
    unsigned* sta    = (unsigned*)(base + alloc((size_t)SB*NSHARD*SHARD_CAP*4));
    int*    csr_pack = (int*)   (base + alloc((size_t)SB*BKT_CAP*4));
    (void)ws_size; (void)n_in; (void)out_size;

    hipMemsetAsync(base + zoff, 0, zbytes, stream);
    k_prepfill<<<PB, 256, 0, stream>>>(Wl, Wr, We, att, Wt, Web, att_h, att6, att4, src, dst, ea,
                                       bkt_cnt, sta, E);
    k_fill2<<<SB*2, 256, 0, stream>>>(sta, bkt_cnt, cnt64, deg_i, csr_off, csr_pack);
    k_gemm <<<MB, 256, 0, stream>>>(x, Wt, bl, br, Web, att_h, cnt64, xl, xr, expd_self, N);
    k_node <<<(N+1)/2, 128, 0, stream>>>(deg_i, csr_off, csr_pack, xl, xr, Web, att6, att4, expd_self,
                                         bias, lnw, lnb, out, N);
}

// Round 26
// 110.608 us; speedup vs baseline: 1.0295x; 1.0295x over previous
//
#include <hip/hip_runtime.h>
#include <hip/hip_bf16.h>

typedef _Float16 f16x8 __attribute__((ext_vector_type(8)));
typedef _Float16 h2    __attribute__((ext_vector_type(2)));
typedef float    f32x4v __attribute__((ext_vector_type(4)));
typedef float    f32x2 __attribute__((ext_vector_type(2)));

#define NEG_SLOPE 0.2f
#define NSHARD 8
#define SHARD_CAP 1024    // staging slots per (bucket, shard)
#define BKT_CAP (NSHARD*SHARD_CAP)   // fixed csr region per bucket
#define CE 1024           // edges per prepfill block (4/thread, register-held)
#define LOG2E 1.44269504088896f

__device__ __forceinline__ ushort f2h_bits(float f){ _Float16 h=(_Float16)f; return __builtin_bit_cast(ushort, h); }
__device__ __forceinline__ h2 uash2(unsigned u){ return __builtin_bit_cast(h2, u); }
__device__ __forceinline__ h2 habs(h2 v){ return __builtin_bit_cast(h2, __builtin_bit_cast(unsigned, v) & 0x7fff7fffu); }
// acc += (f16 half of xs) * ex, exact (f16 widened to f32 inside the FMA)
__device__ __forceinline__ void fmamix_lo(float& acc, h2 xs, float ex){
    asm("v_fma_mix_f32 %0, %1, %2, %0 op_sel:[0,0,0] op_sel_hi:[1,0,0]" : "+v"(acc) : "v"(xs), "v"(ex));
}
__device__ __forceinline__ void fmamix_hi(float& acc, h2 xs, float ex){
    asm("v_fma_mix_f32 %0, %1, %2, %0 op_sel:[1,0,0] op_sel_hi:[1,0,0]" : "+v"(acc) : "v"(xs), "v"(ex));
}

// ---------------- K0: prepfill — weights->f16 + bucket staging; NO global atomics on cnt64 ----------------
// staged entry: src(16b) | etype<<16 (3b) | dstloc<<19 (8b)
__global__ __launch_bounds__(256) void k_prepfill(const float* __restrict__ Wl, const float* __restrict__ Wr,
    const float* __restrict__ We, const float* __restrict__ att,
    ushort* __restrict__ Wt, ushort* __restrict__ Web, ushort* __restrict__ att_h,
    ushort* __restrict__ att6, ushort* __restrict__ att4,
    const int* __restrict__ src, const int* __restrict__ dst, const float* __restrict__ ea,
    int* __restrict__ bkt_cnt, unsigned* __restrict__ sta, int E)
{
    __shared__ int hist[256], gbase[256], wcur[256];
    int tid = threadIdx.x;
    int idx = blockIdx.x*256 + tid;
    if (idx < 256*128) {
        int c = idx >> 7, k = idx & 127;
        float v = (c < 128) ? Wl[k*128 + c] : Wr[k*128 + (c-128)];
        Wt[idx] = f2h_bits(v);
    }
    if (idx < 8*128) Web[idx] = f2h_bits(We[idx]);
    if (idx < 128) {
        float a = att[idx];
        att_h[idx] = f2h_bits(a);
        att6[idx]  = f2h_bits(0.6f*LOG2E*a);      // lrelu-decomposed, log2e folded (k_node uses exp2)
        att4[idx]  = f2h_bits(0.4f*LOG2E*a);
    }

    hist[tid] = 0; wcur[tid] = 0;
    __syncthreads();
    int shard = blockIdx.x & (NSHARD-1);
    int e0 = blockIdx.x*CE;
    int ne = min(CE, E - e0);
    unsigned ent[4];
    int ebkt[4];
    #pragma unroll
    for (int j=0;j<4;++j){
        int i = tid + j*256;
        ebkt[j] = -1;
        if (i < ne){
            int e = e0 + i;
            int d = dst[e];
            const float* a = ea + (size_t)e*8;
            float4 u0 = *(const float4*)a;
            float4 u1 = *(const float4*)(a + 4);
            float v[8] = {u0.x,u0.y,u0.z,u0.w,u1.x,u1.y,u1.z,u1.w};
            int bt = 0;                            // one-hot: nonzero component (value==1.0)
            #pragma unroll
            for (int q=0;q<8;++q) if (v[q] != 0.f) bt = q;
            int b = d >> 8;
            ent[j] = (unsigned)(src[e] & 0xFFFF) | ((unsigned)bt << 16) | ((unsigned)(d & 255) << 19);
            ebkt[j] = b;
            atomicAdd(&hist[b], 1);
        }
    }
    __syncthreads();
    int v = hist[tid];
    if (v > 0) gbase[tid] = atomicAdd(&bkt_cnt[shard*256 + tid], v);
    __syncthreads();
    #pragma unroll
    for (int j=0;j<4;++j){
        if (ebkt[j] >= 0){
            int b = ebkt[j];
            int r = atomicAdd(&wcur[b], 1);
            sta[((size_t)b*NSHARD + shard)*SHARD_CAP + gbase[b] + r] = ent[j];  // L2-merged run
        }
    }
}

// ---------------- K1: fill2 — 2 blocks/bucket; LDS type-count -> cnt64/deg/csr_off (even-aligned), scatter ----------------
__global__ __launch_bounds__(256) void k_fill2(const unsigned* __restrict__ sta,
    const int* __restrict__ bkt_cnt, unsigned long long* __restrict__ cnt64,
    int* __restrict__ deg_i, int* __restrict__ csr_off, int* __restrict__ csr_pack)
{
    __shared__ unsigned long long c64[256];
    __shared__ int s[256];
    __shared__ int sexc[256];
    __shared__ int lcur[256];
    int b = blockIdx.x >> 1, half = blockIdx.x & 1;
    int tid = threadIdx.x;
    c64[tid] = 0; lcur[tid] = 0;
    __syncthreads();
    // count pass: all shards, all entries (both halves -> full 256-node degrees for the scan)
    for (int k = 0; k < NSHARD; ++k){
        int cnt = bkt_cnt[k*256 + b];
        const unsigned* sb = sta + ((size_t)b*NSHARD + k)*SHARD_CAP;
        for (int i = tid; i < cnt; i += 256){
            unsigned u = sb[i];
            int dl = (u >> 19) & 255;
            int bt = (u >> 16) & 7;
            atomicAdd(&c64[dl], 1ull << (8*bt));
        }
    }
    __syncthreads();
    unsigned long long cv = c64[tid];
    int v = (int)((cv * 0x0101010101010101ull) >> 56);   // degree
    s[tid] = (v + 1) & ~1;                         // pad region to even start (8B-aligned pair loads)
    __syncthreads();
    #pragma unroll
    for (int off=1; off<256; off<<=1){
        int t = (tid >= off) ? s[tid-off] : 0;
        __syncthreads();
        s[tid] += t;
        __syncthreads();
    }
    int loc = s[tid] - ((v + 1) & ~1);             // bucket-local exclusive offset (even)
    sexc[tid] = loc;
    int node = b*256 + tid;
    if ((tid >> 7) == half){
        cnt64[node] = cv;
        deg_i[node] = v;
        csr_off[node] = b*BKT_CAP + loc;           // bucket-strided csr region, even offset
    }
    __syncthreads();
    int base = b*BKT_CAP;
    for (int k = 0; k < NSHARD; ++k){
        int cnt = bkt_cnt[k*256 + b];
        const unsigned* sb = sta + ((size_t)b*NSHARD + k)*SHARD_CAP;
        for (int i = tid; i < cnt; i += 256){
            unsigned u = sb[i];
            int dl = (u >> 19) & 255;
            if ((dl >> 7) != half) continue;
            int slot = base + sexc[dl] + atomicAdd(&lcur[dl], 1);
            csr_pack[slot] = (int)(u & 0xFFFFu) | (int)(((u >> 16) & 7u) << 24);
        }
    }
}

// ---------------- K2: MFMA GEMM — 32 rows/wave (shared B-fragments), wave-local staging ----------------
__global__ __launch_bounds__(256) void k_gemm(const float* __restrict__ x, const ushort* __restrict__ Wt,
    const float* __restrict__ bl, const float* __restrict__ br,
    const ushort* __restrict__ Web, const ushort* __restrict__ att_h,
    const unsigned long long* __restrict__ cnt64,
    ushort* __restrict__ xl, ushort* __restrict__ xr, float* __restrict__ expd_self, int Nn)
{
    __shared__ ushort S[4][32*256];               // 16KB per wave (wave-local; no cross-wave sharing)
    int tid = threadIdx.x;
    int wave = tid >> 6, lane = tid & 63;
    int l15 = lane & 15, l4 = lane >> 4;
    int row0 = blockIdx.x*128 + wave*32;

    f16x8 afragA[4], afragB[4];
    int growA = row0 + l15, growB = row0 + 16 + l15;
    bool rokA = growA < Nn, rokB = growB < Nn;
    const float* xpA = x + (size_t)growA*128 + l4*8;
    const float* xpB = x + (size_t)growB*128 + l4*8;
    #pragma unroll
    for (int ks=0; ks<4; ++ks){
        float4 a = make_float4(0,0,0,0), b = make_float4(0,0,0,0);
        if (rokA) { a = *(const float4*)(xpA + ks*32); b = *(const float4*)(xpA + ks*32 + 4); }
        afragA[ks] = (f16x8){ (_Float16)a.x,(_Float16)a.y,(_Float16)a.z,(_Float16)a.w,
                              (_Float16)b.x,(_Float16)b.y,(_Float16)b.z,(_Float16)b.w };
        float4 c = make_float4(0,0,0,0), d = make_float4(0,0,0,0);
        if (rokB) { c = *(const float4*)(xpB + ks*32); d = *(const float4*)(xpB + ks*32 + 4); }
        afragB[ks] = (f16x8){ (_Float16)c.x,(_Float16)c.y,(_Float16)c.z,(_Float16)c.w,
                              (_Float16)d.x,(_Float16)d.y,(_Float16)d.z,(_Float16)d.w };
    }

    ushort* sw_base = &S[wave][0];
    #pragma unroll
    for (int nf=0; nf<16; ++nf){
        f32x4v accA = (f32x4v){0.f,0.f,0.f,0.f};
        f32x4v accB = (f32x4v){0.f,0.f,0.f,0.f};
        #pragma unroll
        for (int ks=0; ks<4; ++ks){
            const ushort* bp = Wt + (size_t)(nf*16 + l15)*128 + ks*32 + l4*8;
            f16x8 bf = *(const f16x8*)(const void*)bp;
            accA = __builtin_amdgcn_mfma_f32_16x16x32_f16(bf, afragA[ks], accA, 0,0,0);
            accB = __builtin_amdgcn_mfma_f32_16x16x32_f16(bf, afragB[ks], accB, 0,0,0);
        }
        int c0 = nf*16 + l4*4;
        const float* bp2 = (c0 < 128) ? (bl + c0) : (br + (c0-128));
        float4 bv = *(const float4*)bp2;
        int sw = c0 ^ ((l15 & 7) << 2);           // row&7 == (16+row)&7: same swizzle both halves
        h2 pa0 = { (_Float16)(accA[0] + bv.x), (_Float16)(accA[1] + bv.y) };
        h2 pa1 = { (_Float16)(accA[2] + bv.z), (_Float16)(accA[3] + bv.w) };
        *(uint2*)(&sw_base[l15*256 + sw]) = make_uint2(__builtin_bit_cast(unsigned, pa0),
                                                       __builtin_bit_cast(unsigned, pa1));
        h2 pb0 = { (_Float16)(accB[0] + bv.x), (_Float16)(accB[1] + bv.y) };
        h2 pb1 = { (_Float16)(accB[2] + bv.z), (_Float16)(accB[3] + bv.w) };
        *(uint2*)(&sw_base[(16 + l15)*256 + sw]) = make_uint2(__builtin_bit_cast(unsigned, pb0),
                                                              __builtin_bit_cast(unsigned, pb1));
    }
    asm volatile("s_waitcnt lgkmcnt(0)");         // wave-local LDS produce->consume

    #pragma unroll
    for (int pass=0; pass<8; ++pass){
        int row = pass*4 + l4;
        int gr = row0 + row;
        if (gr < Nn){
            int cu = l15*8;
            int m = (row & 7) << 2;
            uint2 a0 = *(const uint2*)(&sw_base[row*256 + (cu ^ m)]);
            uint2 a1 = *(const uint2*)(&sw_base[row*256 + ((cu+4) ^ m)]);
            *(uint4*)(xl + (size_t)gr*128 + cu) = make_uint4(a0.x, a0.y, a1.x, a1.y);
            uint2 b0 = *(const uint2*)(&sw_base[row*256 + ((128+cu) ^ m)]);
            uint2 b1 = *(const uint2*)(&sw_base[row*256 + ((128+cu+4) ^ m)]);
            *(uint4*)(xr + (size_t)gr*128 + cu) = make_uint4(b0.x, b0.y, b1.x, b1.y);
        }
    }

    // Fused self-loop score, 2 passes over the 32 staged rows; tables computed once.
    h2 at2v[16];
    {
        const ushort* ap = att_h + l4*32;
        uint4 a0 = *(const uint4*)ap;
        uint4 a1 = *(const uint4*)(ap + 8);
        uint4 a2 = *(const uint4*)(ap + 16);
        uint4 a3 = *(const uint4*)(ap + 24);
        at2v[0]=uash2(a0.x); at2v[1]=uash2(a0.y); at2v[2]=uash2(a0.z); at2v[3]=uash2(a0.w);
        at2v[4]=uash2(a1.x); at2v[5]=uash2(a1.y); at2v[6]=uash2(a1.z); at2v[7]=uash2(a1.w);
        at2v[8]=uash2(a2.x); at2v[9]=uash2(a2.y); at2v[10]=uash2(a2.z); at2v[11]=uash2(a2.w);
        at2v[12]=uash2(a3.x); at2v[13]=uash2(a3.y); at2v[14]=uash2(a3.z); at2v[15]=uash2(a3.w);
    }
    const h2 z2  = {(_Float16)0.f, (_Float16)0.f};
    const h2 c02 = {(_Float16)NEG_SLOPE, (_Float16)NEG_SLOPE};
    #pragma unroll
    for (int pp=0; pp<2; ++pp){
        int row = pp*16 + l15;
        int grow = row0 + row;
        if (grow >= Nn) continue;
        unsigned long long cv = cnt64[grow];
        int deg = (int)((cv * 0x0101010101010101ull) >> 56);
        float inv = 1.f / fmaxf((float)deg, 1.f);
        h2 wt[8];
        #pragma unroll
        for (int t=0;t<8;++t){
            float w = (float)((cv >> (8*t)) & 0xff) * inv;
            wt[t] = (h2){ (_Float16)w, (_Float16)w };
        }
        h2 emb[16];
        #pragma unroll
        for (int j=0;j<16;++j) emb[j] = (h2){(_Float16)0.f,(_Float16)0.f};
        #pragma unroll
        for (int t=0;t<8;++t){
            const ushort* wp = Web + t*128 + l4*32;
            uint4 u0 = *(const uint4*)wp;
            uint4 u1 = *(const uint4*)(wp + 8);
            uint4 u2 = *(const uint4*)(wp + 16);
            uint4 u3 = *(const uint4*)(wp + 24);
            emb[0]+=wt[t]*uash2(u0.x); emb[1]+=wt[t]*uash2(u0.y); emb[2]+=wt[t]*uash2(u0.z); emb[3]+=wt[t]*uash2(u0.w);
            emb[4]+=wt[t]*uash2(u1.x); emb[5]+=wt[t]*uash2(u1.y); emb[6]+=wt[t]*uash2(u1.z); emb[7]+=wt[t]*uash2(u1.w);
            emb[8]+=wt[t]*uash2(u2.x); emb[9]+=wt[t]*uash2(u2.y); emb[10]+=wt[t]*uash2(u2.z); emb[11]+=wt[t]*uash2(u2.w);
            emb[12]+=wt[t]*uash2(u3.x); emb[13]+=wt[t]*uash2(u3.y); emb[14]+=wt[t]*uash2(u3.z); emb[15]+=wt[t]*uash2(u3.w);
        }
        float p0 = 0.f, p1 = 0.f;
        int m = (row & 7) << 2;
        #pragma unroll
        for (int j=0;j<8;++j){
            int c0 = l4*32 + j*4;
            uint2 xlu = *(const uint2*)(&sw_base[row*256 + (c0 ^ m)]);
            uint2 xru = *(const uint2*)(&sw_base[row*256 + ((128+c0) ^ m)]);
            #pragma unroll
            for (int s2=0;s2<2;++s2){
                h2 v = (uash2(s2 ? xlu.y : xlu.x) + uash2(s2 ? xru.y : xru.x)) + emb[j*2+s2];
                h2 r = __builtin_elementwise_max(v, z2);
                h2 mm = __builtin_elementwise_min(v, z2);
                r = r + c02*mm;
                if (j < 4) p0 = __builtin_amdgcn_fdot2(at2v[j*2+s2], r, p0, false);
                else       p1 = __builtin_amdgcn_fdot2(at2v[j*2+s2], r, p1, false);
            }
        }
        *(float2*)(expd_self + (size_t)grow*8 + l4*2) = make_float2(__expf(p0), __expf(p1));
    }
}

// ---------------- K3: fused per-node pass — 8 edges/round (2 per group), sanitized indices ----------------
__global__ __launch_bounds__(128) void k_node(const int* __restrict__ deg_i, const int* __restrict__ csr_off,
    const int* __restrict__ csr_pack,
    const ushort* __restrict__ xl, const ushort* __restrict__ xr, const ushort* __restrict__ Web,
    const ushort* __restrict__ att6, const ushort* __restrict__ att4, const float* __restrict__ expd_self,
    const float* __restrict__ bias, const float* __restrict__ lnw, const float* __restrict__ lnb,
    float* __restrict__ out, int Nn)
{
    __shared__ ushort xrw[2][8][16][8];           // [wave][etype][lane-l][8 f16] = 4KB
    int wv = threadIdx.x >> 6, lane = threadIdx.x & 63;
    int n = blockIdx.x*2 + wv;
    if (n >= Nn) return;
    int g = lane >> 4, l = lane & 15;

    h2 a6[4], a4[4];
    {
        uint4 u6 = *(const uint4*)(att6 + l*8);
        uint4 u4 = *(const uint4*)(att4 + l*8);
        a6[0]=uash2(u6.x); a6[1]=uash2(u6.y); a6[2]=uash2(u6.z); a6[3]=uash2(u6.w);
        a4[0]=uash2(u4.x); a4[1]=uash2(u4.y); a4[2]=uash2(u4.z); a4[3]=uash2(u4.w);
    }
    // build xrw[wv][t][l] = xr[n][l*8..] + Web[t][l*8..]; lane (g,l) does types g and g+4
    {
        uint4 ru = *(const uint4*)(xr + (size_t)n*128 + l*8);
        h2 xr2[4] = {uash2(ru.x), uash2(ru.y), uash2(ru.z), uash2(ru.w)};
        #pragma unroll
        for (int tt=0; tt<2; ++tt){
            int t = g + tt*4;
            uint4 wu = *(const uint4*)(Web + t*128 + l*8);
            h2 w0 = uash2(wu.x)+xr2[0], w1 = uash2(wu.y)+xr2[1];
            h2 w2 = uash2(wu.z)+xr2[2], w3 = uash2(wu.w)+xr2[3];
            *(uint4*)(&xrw[wv][t][l][0]) = make_uint4(__builtin_bit_cast(unsigned,w0), __builtin_bit_cast(unsigned,w1),
                                                      __builtin_bit_cast(unsigned,w2), __builtin_bit_cast(unsigned,w3));
        }
        asm volatile("s_waitcnt lgkmcnt(0)");     // intra-wave LDS produce->consume (no barrier needed)
    }

    int beg = csr_off[n];
    int cnt = deg_i[n];
    float accx[4], accy[4];
    #pragma unroll
    for (int k=0;k<4;++k){ accx[k]=0.f; accy[k]=0.f; }
    float den = 0.f;

    for (int i = 0; i < cnt; i += 8) {
        int e0i = i + 2*g;
        bool v0 = e0i < cnt;
        bool v1 = (e0i + 1) < cnt;
        uint2 pk = *(const uint2*)(csr_pack + beg + (v0 ? e0i : 0));   // 8B aligned (beg even)
        int s0  = v0 ? (pk.x & 0xFFFFFF) : 0;                          // sanitize: padding slots hold poison
        int et0 = v0 ? (int)(((unsigned)pk.x) >> 24) : 0;
        int s1  = v1 ? (pk.y & 0xFFFFFF) : 0;
        int et1 = v1 ? (int)(((unsigned)pk.y) >> 24) : 0;
        uint4 xu0 = *(const uint4*)(xl + (size_t)s0*128 + l*8);        // two independent gathers in flight
        uint4 xu1 = *(const uint4*)(xl + (size_t)s1*128 + l*8);
        uint4 wu0 = *(const uint4*)(&xrw[wv][et0][l][0]);
        uint4 wu1 = *(const uint4*)(&xrw[wv][et1][l][0]);
        h2 xs0[4] = {uash2(xu0.x), uash2(xu0.y), uash2(xu0.z), uash2(xu0.w)};
        h2 xs1[4] = {uash2(xu1.x), uash2(xu1.y), uash2(xu1.z), uash2(xu1.w)};
        h2 xw0[4] = {uash2(wu0.x), uash2(wu0.y), uash2(wu0.z), uash2(wu0.w)};
        h2 xw1[4] = {uash2(wu1.x), uash2(wu1.y), uash2(wu1.z), uash2(wu1.w)};
        float pa = 0.f, pb = 0.f;
        #pragma unroll
        for (int k=0;k<4;++k){
            h2 va = xs0[k] + xw0[k];
            pa = __builtin_amdgcn_fdot2(a6[k], va, pa, false);
            pa = __builtin_amdgcn_fdot2(a4[k], habs(va), pa, false);
            h2 vb = xs1[k] + xw1[k];
            pb = __builtin_amdgcn_fdot2(a6[k], vb, pb, false);
            pb = __builtin_amdgcn_fdot2(a4[k], habs(vb), pb, false);
        }
        pa += __shfl_xor(pa, 1);                   // head score*log2e (2 lanes/head)
        pb += __shfl_xor(pb, 1);
        float ex0 = v0 ? exp2f(pa) : 0.f;
        float ex1 = v1 ? exp2f(pb) : 0.f;
        den += ex0 + ex1;
        #pragma unroll
        for (int k=0;k<4;++k){
            fmamix_lo(accx[k], xs0[k], ex0);
            fmamix_hi(accy[k], xs0[k], ex0);
            fmamix_lo(accx[k], xs1[k], ex1);
            fmamix_hi(accy[k], xs1[k], ex1);
        }
    }

    #pragma unroll
    for (int k=0;k<4;++k){
        accx[k] += __shfl_xor(accx[k], 16); accx[k] += __shfl_xor(accx[k], 32);
        accy[k] += __shfl_xor(accy[k], 16); accy[k] += __shfl_xor(accy[k], 32);
    }
    den += __shfl_xor(den, 16);
    den += __shfl_xor(den, 32);

    // self loop: expd_self precomputed in k_gemm
    {
        float ex = expd_self[(size_t)n*8 + (l >> 1)];
        uint4 su = *(const uint4*)(xl + (size_t)n*128 + l*8);
        den += ex;
        h2 ss[4] = {uash2(su.x), uash2(su.y), uash2(su.z), uash2(su.w)};
        #pragma unroll
        for (int k=0;k<4;++k){
            fmamix_lo(accx[k], ss[k], ex);
            fmamix_hi(accy[k], ss[k], ex);
        }
    }

    float dinv = 1.f/den;
    f32x2 a[4];
    {
        float4 b0 = *(const float4*)(bias + l*8);
        float4 b1 = *(const float4*)(bias + l*8 + 4);
        a[0] = (f32x2){accx[0]*dinv + b0.x, accy[0]*dinv + b0.y};
        a[1] = (f32x2){accx[1]*dinv + b0.z, accy[1]*dinv + b0.w};
        a[2] = (f32x2){accx[2]*dinv + b1.x, accy[2]*dinv + b1.y};
        a[3] = (f32x2){accx[3]*dinv + b1.z, accy[3]*dinv + b1.w};
    }
    float sum = 0.f;
    #pragma unroll
    for (int k=0;k<4;++k) sum += a[k].x + a[k].y;
    #pragma unroll
    for (int off=8; off>0; off>>=1) sum += __shfl_xor(sum, off);
    float mu = sum * (1.f/128.f);
    float vs = 0.f;
    #pragma unroll
    for (int k=0;k<4;++k){ a[k] -= mu; vs += a[k].x*a[k].x + a[k].y*a[k].y; }
    #pragma unroll
    for (int off=8; off>0; off>>=1) vs += __shfl_xor(vs, off);
    float rs = rsqrtf(vs*(1.f/128.f) + 1e-5f);
    float y[8];
    {
        float4 w0 = *(const float4*)(lnw + l*8);
        float4 w1 = *(const float4*)(lnw + l*8 + 4);
        float4 c0 = *(const float4*)(lnb + l*8);
        float4 c1 = *(const float4*)(lnb + l*8 + 4);
        y[0]=a[0].x*rs*w0.x+c0.x; y[1]=a[0].y*rs*w0.y+c0.y;
        y[2]=a[1].x*rs*w0.z+c0.z; y[3]=a[1].y*rs*w0.w+c0.w;
        y[4]=a[2].x*rs*w1.x+c1.x; y[5]=a[2].y*rs*w1.y+c1.y;
        y[6]=a[3].x*rs*w1.z+c1.z; y[7]=a[3].y*rs*w1.w+c1.w;
    }
    #pragma unroll
    for (int j=0;j<8;++j) y[j] = (y[j] > 0.f) ? y[j] : (__expf(y[j]) - 1.f);
    if (lane < 16) {
        float* po = out + (size_t)n*128 + l*8;
        *(float4*)po     = make_float4(y[0],y[1],y[2],y[3]);
        *(float4*)(po+4) = make_float4(y[4],y[5],y[6],y[7]);
    }
}

extern "C" void kernel_launch(void* const* d_in, const int* in_sizes, int n_in,
                              void* d_out, int out_size, void* d_ws, size_t ws_size,
                              hipStream_t stream)
{
    const float* x   = (const float*)d_in[0];
    const int*   src = (const int*)  d_in[1];
    const int*   dst = (const int*)  d_in[2];
    const float* ea  = (const float*)d_in[3];
    const float* Wl  = (const float*)d_in[4];
    const float* bl  = (const float*)d_in[5];
    const float* Wr  = (const float*)d_in[6];
    const float* br  = (const float*)d_in[7];
    const float* We  = (const float*)d_in[8];
    const float* att = (const float*)d_in[9];
    const float* bias= (const float*)d_in[10];
    const float* lnw = (const float*)d_in[11];
    const float* lnb = (const float*)d_in[12];
    float* out = (float*)d_out;

    const int N  = in_sizes[0] / 128;
    const int E  = in_sizes[1];
    const int NP = ((N + 255)/256)*256;
    const int MB = (N + 127)/128;     // 128 rows per gemm block
    const int SB = NP/256;            // buckets (256 nodes each)
    const int PB = (E + CE - 1)/CE;   // prepfill blocks

    char* base = (char*)d_ws;
    size_t o = 0;
    auto alloc = [&](size_t b){ size_t r = o; o += (b + 255) & ~(size_t)255; return r; };
    ushort* Wt       = (ushort*)(base + alloc(256*128*2));
    ushort* Web      = (ushort*)(base + alloc(8*128*2));
    ushort* att_h    = (ushort*)(base + alloc(128*2));
    ushort* att6     = (ushort*)(base + alloc(128*2));
    ushort* att4     = (ushort*)(base + alloc(128*2));
    ushort* xl       = (ushort*)(base + alloc((size_t)MB*128*128*2));
    ushort* xr       = (ushort*)(base + alloc((size_t)MB*128*128*2));
    float*  expd_self= (float*) (base + alloc((size_t)NP*8*4));
    size_t zoff = o;
    int*    bkt_cnt  = (int*)   (base + alloc((size_t)NSHARD*256*4));
    size_t zbytes = o - zoff;
    unsigned long long* cnt64 = (unsigned long long*)(base + alloc((size_t)NP*8));
    int*    deg_i    = (int*)   (base + alloc((size_t)NP*4));
    int*    csr_off  = (int*)   (base + alloc((size_t)NP*4));
    unsigned* sta    = (unsigned*)(base + alloc((size_t)SB*NSHARD*SHARD_CAP*4));
    int*    csr_pack = (int*)   (base + alloc((size_t)SB*BKT_CAP*4));
    (void)ws_size; (void)n_in; (void)out_size;

    hipMemsetAsync(base + zoff, 0, zbytes, stream);
    k_prepfill<<<PB, 256, 0, stream>>>(Wl, Wr, We, att, Wt, Web, att_h, att6, att4, src, dst, ea,
                                       bkt_cnt, sta, E);
    k_fill2<<<SB*2, 256, 0, stream>>>(sta, bkt_cnt, cnt64, deg_i, csr_off, csr_pack);
    k_gemm <<<MB, 256, 0, stream>>>(x, Wt, bl, br, Web, att_h, cnt64, xl, xr, expd_self, N);
    k_node <<<(N+1)/2, 128, 0, stream>>>(deg_i, csr_off, csr_pack, xl, xr, Web, att6, att4, expd_self,
                                         bias, lnw, lnb, out, N);
}